// Round 8
// baseline (4973.176 us; speedup 1.0000x reference)
//
#include <hip/hip_runtime.h>

#define TINN 512
#define FF 64
#define HHD 512
#define TOUTN 64

using v8h = __attribute__((ext_vector_type(8))) _Float16;
using v4h = __attribute__((ext_vector_type(4))) _Float16;
using v4f = __attribute__((ext_vector_type(4))) float;
using u32x4 = __attribute__((ext_vector_type(4))) unsigned int;
using u64 = unsigned long long;

#define AGT __HIP_MEMORY_SCOPE_AGENT

// ---------------- LDS layout (bytes) ----------------
#define WOFF 0            // weights, MFMA fragment order (max 128KB)
#define BIAS_OFF 131072
#define WIH0_OFF 131328
#define PREV_OFF 131584
#define PART_OFF 131840
#define PROJW_OFF 132864
#define PROJB_OFF 134912
#define TRANS_OFF 134976  // 4 waves x 512B h-transpose scratch
#define SMEM_TOTAL 137024

// ---------------- workspace layout ----------------
// AGGREGATE COUNTERS (one per group x role), then h0/h1 rings.
// Producer p, after its bypass h stores are ACKED (s_waitcnt 0), does ONE
// atomicAdd(+1) to its role counter. Every producer signals levels
// 1,2,3,... in lockstep, so cnt >= 32*v  <=>  all 32 producers at level
// >= v — identical semantics to the old per-producer flags, but consumers
// poll with TWO lanes per block (lane0: role0 cnt, lane1: role1 cnt)
// instead of 32-64 lanes: per-group poll traffic drops ~30-60x. Theory:
// the old ~8000 poll-loads/us/group queued at the LLC ahead of the
// producers' data/flag stores, inflating every link of the serial chain.
// h/x SWIZZLED LAYOUT: off(m,c) = (m>>4)*16384 + (c>>6)*2048 +
//   ((c>>5)&1)*1024 + ((c>>3)&3)*256 + (m&15)*16 + (c&7)*2
#define WS_CNT 0
#define WS_HOFF 16384
#define HBYTES (256 * HHD * 2)   // 256 KiB per ring slot

static __device__ __forceinline__ float sigm(float x) { return 1.0f / (1.0f + __expf(-x)); }
static __device__ __forceinline__ float tanh_f(float x) { return 1.0f - 2.0f / (1.0f + __expf(2.0f * x)); }

static __device__ __forceinline__ void schedBar() {
#if __has_builtin(__builtin_amdgcn_sched_barrier)
  __builtin_amdgcn_sched_barrier(0);
#endif
}

static __device__ __forceinline__ v8h aload16(const _Float16* p) {
  union { u64 u[2]; v8h h; } c;
  const u64* q = (const u64*)p;
  c.u[0] = __hip_atomic_load(q, __ATOMIC_RELAXED, AGT);
  c.u[1] = __hip_atomic_load(q + 1, __ATOMIC_RELAXED, AGT);
  return c.h;
}
static __device__ __forceinline__ void astore8(_Float16* p, v4h v) {
  union { u64 u; v4h h; } c;
  c.h = v;
  __hip_atomic_store((u64*)p, c.u, __ATOMIC_RELAXED, AGT);
}
static __device__ __forceinline__ void astore8z(void* p) {
  __hip_atomic_store((u64*)p, 0ull, __ATOMIC_RELAXED, AGT);
}

#if __has_builtin(__builtin_amdgcn_raw_ptr_buffer_load_b128) && \
    __has_builtin(__builtin_amdgcn_make_buffer_rsrc)
#define HAVE_BUFLOAD 1
using rsrc_t = __amdgpu_buffer_rsrc_t;
static __device__ __forceinline__ rsrc_t mkrsrc(const void* p) {
  return __builtin_amdgcn_make_buffer_rsrc((void*)p, (short)0, 0xFFFFFFFFu, 0x00020000);
}
static __device__ __forceinline__ v8h bload16(rsrc_t r, int byteOff) {
  union { u32x4 u; v8h h; } c;
  c.u = __builtin_amdgcn_raw_ptr_buffer_load_b128(r, byteOff, 0, 17);  // sc0|sc1
  return c.h;
}
#endif

// Producer signal: after ALL h stores are acked (waitcnt 0 + barrier),
// ONE lane does ONE atomicAdd(+1) on this role's aggregate counter.
static __device__ __forceinline__ void signalDone(unsigned* cntMine) {
  __builtin_amdgcn_s_waitcnt(0);
  __syncthreads();
  if (threadIdx.x == 0)
    (void)__hip_atomic_fetch_add(cntMine, 1u, __ATOMIC_RELAXED, AGT);
}

// Spin until *p >= 32*tgt. Low-rate: s_sleep(2) (~128cy) backoff.
static __device__ __forceinline__ void spinCnt(unsigned* p, int tgt) {
  unsigned goal = (unsigned)(32 * tgt);
  for (;;) {
    unsigned v = __hip_atomic_load(p, __ATOMIC_RELAXED, AGT);
    if (v >= goal) break;
    asm volatile("" ::: "memory");
    __builtin_amdgcn_s_sleep(2);
  }
}

// Dual-role wait: lane0 polls role0 counter (tgt0), lane1 role1 (tgt1).
// tgt <= 0 skips that role. Only 2 poll-loads per block per iteration.
static __device__ __forceinline__ void waitCnts(
    unsigned* cnt0, unsigned* cnt1, int tgt0, int tgt1) {
  int t = threadIdx.x;
  if (t == 0 && tgt0 > 0) spinCnt(cnt0, tgt0);
  if (t == 1 && tgt1 > 0) spinCnt(cnt1, tgt1);
  __syncthreads();
  schedBar();
}

// Weight slice (64 gate-cols x K) fp32->fp16 into LDS, fragment order.
static __device__ __attribute__((noinline)) void loadWeights(
    int tid, int hc0, const float* W1, int ld1, int K1,
    const float* W2, int K) {
  extern __shared__ char smem[];
  int c = tid >> 2, sub = tid & 3;
  int nt = c >> 4, l = c & 15;
  int n = nt * HHD + hc0 + l;
  int Kq = K >> 2;
  for (int k = sub * Kq; k < (sub + 1) * Kq; ++k) {
    float v;
    if (k < K1) v = W1[(size_t)n * ld1 + k];
    else        v = W2[(size_t)n * HHD + (k - K1)];
    int kc = k >> 6, ks = (k >> 5) & 1, quad = (k >> 3) & 3, j = k & 7;
    int off = (((kc * 2 + ks) * 4 + nt) * 64 + quad * 16 + l) * 16 + j * 2;
    *(_Float16*)(smem + WOFF + off) = (_Float16)v;
  }
}

// 8 K-chunks of MFMA from swizzled src (h buffers), weight chunks WC0..WC0+7.
template <int WC0>
static __device__ __forceinline__ void mfma8(
    const _Float16* src, int rt, int lane, const char* wbLane, v4f* acc) {
#if HAVE_BUFLOAD
  rsrc_t rs = mkrsrc(src);
#endif
#pragma unroll
  for (int kc = 0; kc < 8; ++kc) {
    int off = rt * 16384 + kc * 2048 + lane * 16;
    v8h ak0, ak1;
#if HAVE_BUFLOAD
    ak0 = bload16(rs, off);
    ak1 = bload16(rs, off + 1024);
#else
    ak0 = aload16(src + off / 2);
    ak1 = aload16(src + (off + 1024) / 2);
#endif
    const char* bb = wbLane + (size_t)(WC0 + kc) * 8192;
#pragma unroll
    for (int ks = 0; ks < 2; ++ks) {
      v8h a = ks ? ak1 : ak0;
      acc[0] = __builtin_amdgcn_mfma_f32_16x16x32_f16(a, *(const v8h*)(bb + (ks * 4 + 0) * 1024), acc[0], 0, 0, 0);
      acc[1] = __builtin_amdgcn_mfma_f32_16x16x32_f16(a, *(const v8h*)(bb + (ks * 4 + 1) * 1024), acc[1], 0, 0, 0);
      acc[2] = __builtin_amdgcn_mfma_f32_16x16x32_f16(a, *(const v8h*)(bb + (ks * 4 + 2) * 1024), acc[2], 0, 0, 0);
      acc[3] = __builtin_amdgcn_mfma_f32_16x16x32_f16(a, *(const v8h*)(bb + (ks * 4 + 3) * 1024), acc[3], 0, 0, 0);
    }
  }
}

// Fused double-source MFMA for stepL1: all 32 A-loads (h1 then h0) issued
// before any MFMA. h1 -> weight chunks 8..15, h0 -> weight chunks 0..7.
static __device__ __forceinline__ void mfmaDual(
    const _Float16* h0src, const _Float16* h1src, int rt, int lane,
    const char* wbLane, v4f* acc) {
  v8h a1[16], a0[16];
#if HAVE_BUFLOAD
  rsrc_t r1 = mkrsrc(h1src);
  rsrc_t r0 = mkrsrc(h0src);
#pragma unroll
  for (int kc = 0; kc < 8; ++kc) {
    int off = rt * 16384 + kc * 2048 + lane * 16;
    a1[2 * kc]     = bload16(r1, off);
    a1[2 * kc + 1] = bload16(r1, off + 1024);
  }
#pragma unroll
  for (int kc = 0; kc < 8; ++kc) {
    int off = rt * 16384 + kc * 2048 + lane * 16;
    a0[2 * kc]     = bload16(r0, off);
    a0[2 * kc + 1] = bload16(r0, off + 1024);
  }
#else
#pragma unroll
  for (int kc = 0; kc < 8; ++kc) {
    int off = rt * 16384 + kc * 2048 + lane * 16;
    a1[2 * kc]     = aload16(h1src + off / 2);
    a1[2 * kc + 1] = aload16(h1src + (off + 1024) / 2);
  }
#pragma unroll
  for (int kc = 0; kc < 8; ++kc) {
    int off = rt * 16384 + kc * 2048 + lane * 16;
    a0[2 * kc]     = aload16(h0src + off / 2);
    a0[2 * kc + 1] = aload16(h0src + (off + 1024) / 2);
  }
#endif
#pragma unroll
  for (int kc = 0; kc < 8; ++kc) {
    const char* bb = wbLane + (size_t)(8 + kc) * 8192;
#pragma unroll
    for (int ks = 0; ks < 2; ++ks) {
      v8h a = a1[2 * kc + ks];
      acc[0] = __builtin_amdgcn_mfma_f32_16x16x32_f16(a, *(const v8h*)(bb + (ks * 4 + 0) * 1024), acc[0], 0, 0, 0);
      acc[1] = __builtin_amdgcn_mfma_f32_16x16x32_f16(a, *(const v8h*)(bb + (ks * 4 + 1) * 1024), acc[1], 0, 0, 0);
      acc[2] = __builtin_amdgcn_mfma_f32_16x16x32_f16(a, *(const v8h*)(bb + (ks * 4 + 2) * 1024), acc[2], 0, 0, 0);
      acc[3] = __builtin_amdgcn_mfma_f32_16x16x32_f16(a, *(const v8h*)(bb + (ks * 4 + 3) * 1024), acc[3], 0, 0, 0);
    }
  }
#pragma unroll
  for (int kc = 0; kc < 8; ++kc) {
    const char* bb = wbLane + (size_t)kc * 8192;
#pragma unroll
    for (int ks = 0; ks < 2; ++ks) {
      v8h a = a0[2 * kc + ks];
      acc[0] = __builtin_amdgcn_mfma_f32_16x16x32_f16(a, *(const v8h*)(bb + (ks * 4 + 0) * 1024), acc[0], 0, 0, 0);
      acc[1] = __builtin_amdgcn_mfma_f32_16x16x32_f16(a, *(const v8h*)(bb + (ks * 4 + 1) * 1024), acc[1], 0, 0, 0);
      acc[2] = __builtin_amdgcn_mfma_f32_16x16x32_f16(a, *(const v8h*)(bb + (ks * 4 + 2) * 1024), acc[2], 0, 0, 0);
      acc[3] = __builtin_amdgcn_mfma_f32_16x16x32_f16(a, *(const v8h*)(bb + (ks * 4 + 3) * 1024), acc[3], 0, 0, 0);
    }
  }
}

// x chunk (weight chunk 0): raw fp32 x, cached (read-only).
static __device__ __forceinline__ void xChunk(
    const float* xstep, int m0, int tid, const char* wbLane, v4f* acc) {
  int lane = tid & 63, wave = tid >> 6;
  int l15 = lane & 15, quad = lane >> 4;
  v8h ak0, ak1;
  int ra = m0 + wave * 16 + l15;
  const float* xr = xstep + (size_t)ra * (TINN * FF) + quad * 8;
  v4f f00 = *(const v4f*)(xr);
  v4f f01 = *(const v4f*)(xr + 4);
  v4f f10 = *(const v4f*)(xr + 32);
  v4f f11 = *(const v4f*)(xr + 36);
#pragma unroll
  for (int e = 0; e < 4; ++e) {
    ak0[e] = (_Float16)f00[e]; ak0[4 + e] = (_Float16)f01[e];
    ak1[e] = (_Float16)f10[e]; ak1[4 + e] = (_Float16)f11[e];
  }
#pragma unroll
  for (int ks = 0; ks < 2; ++ks) {
    v8h a = ks ? ak1 : ak0;
    acc[0] = __builtin_amdgcn_mfma_f32_16x16x32_f16(a, *(const v8h*)(wbLane + (ks * 4 + 0) * 1024), acc[0], 0, 0, 0);
    acc[1] = __builtin_amdgcn_mfma_f32_16x16x32_f16(a, *(const v8h*)(wbLane + (ks * 4 + 1) * 1024), acc[1], 0, 0, 0);
    acc[2] = __builtin_amdgcn_mfma_f32_16x16x32_f16(a, *(const v8h*)(wbLane + (ks * 4 + 2) * 1024), acc[2], 0, 0, 0);
    acc[3] = __builtin_amdgcn_mfma_f32_16x16x32_f16(a, *(const v8h*)(wbLane + (ks * 4 + 3) * 1024), acc[3], 0, 0, 0);
  }
}

// In-register gate math + per-wave LDS mini-transpose for a coalesced 8B
// h write (bypass store: fresh at LLC before the counter bump).
static __device__ __forceinline__ void epilogue(
    int tid, int m0, int hc0, int rank1, _Float16* hout, float* creg, v4f* acc) {
  extern __shared__ char smem[];
  int lane = tid & 63, wave = tid >> 6;
  int l15 = lane & 15, quad = lane >> 4;
  float* bias = (float*)(smem + BIAS_OFF);
  float bi = bias[l15], bf = bias[16 + l15], bg = bias[32 + l15], bo = bias[48 + l15];
  float wi = 0.f, wf = 0.f, wg = 0.f, wo = 0.f;
  if (rank1) {
    float* wih0 = (float*)(smem + WIH0_OFF);
    wi = wih0[l15]; wf = wih0[16 + l15]; wg = wih0[32 + l15]; wo = wih0[48 + l15];
  }
  float* prevl = (float*)(smem + PREV_OFF);
  _Float16* tb = (_Float16*)(smem + TRANS_OFF + (size_t)wave * 512);
#pragma unroll
  for (int r = 0; r < 4; ++r) {
    int mloc = wave * 16 + quad * 4 + r;
    float gi = acc[0][r] + bi, gf = acc[1][r] + bf;
    float gg = acc[2][r] + bg, go = acc[3][r] + bo;
    if (rank1) {
      float pv = prevl[mloc];
      gi += pv * wi; gf += pv * wf; gg += pv * wg; go += pv * wo;
    }
    float cc = sigm(gf) * creg[r] + sigm(gi) * tanh_f(gg);
    float h = sigm(go) * tanh_f(cc);
    creg[r] = cc;
    tb[(quad * 4 + r) * 16 + l15] = (_Float16)h;   // m-fast deposit
  }
  // c-fast pickup: one 8B read + one 8B coalesced bypass store
  {
    int mloc = lane & 15, cg = lane >> 4;
    v4h hv = *(const v4h*)(tb + mloc * 16 + cg * 4);
    int m = m0 + wave * 16 + mloc;
    int c0 = hc0 + cg * 4;
    int off = (m >> 4) * 16384 + (c0 >> 6) * 2048 + ((c0 >> 5) & 1) * 1024 +
              ((c0 >> 3) & 3) * 256 + (m & 15) * 16 + (c0 & 7) * 2;
    astore8((_Float16*)((char*)hout + off), hv);
  }
}

// ---- step functions (noinline: compile-crash hygiene) ----

// enc0 step p: xChunk hoisted (x is read-only, no ordering need); single
// dual-counter wait (role0 progress + role1 write-reuse guard); h chunks;
// epilogue; one atomicAdd.
static __device__ __attribute__((noinline)) void stepEnc0(
    int tid, int m0, int hc0, unsigned* cnt0, unsigned* cnt1, int p,
    const float* xstep, const _Float16* h0prev, _Float16* h0out, float* creg) {
  extern __shared__ char smem[];
  int lane = tid & 63, wave = tid >> 6;
  v4f acc[4];
  acc[0] = v4f{0.f, 0.f, 0.f, 0.f}; acc[1] = acc[0]; acc[2] = acc[0]; acc[3] = acc[0];
  const char* wbLane = smem + WOFF + (size_t)lane * 16;
  xChunk(xstep, m0, tid, wbLane, acc);        // off critical path
  waitCnts(cnt0, cnt1, p + 1, p - 2);         // h0(p-1) ready + reuse guard
  mfma8<1>(h0prev, (m0 >> 4) + wave, lane, wbLane, acc);
  epilogue(tid, m0, hc0, 0, h0out, creg, acc);
  signalDone(cnt0);
}

// L1-style step (enc1 & dec1): one dual-counter wait, then all 32 A-loads
// (h1 + h0) issued together before the MFMA stream.
static __device__ __attribute__((noinline)) void stepL1(
    int tid, int m0, int hc0, unsigned* cnt0, unsigned* cnt1, int tR1, int tR0,
    const _Float16* h0src, const _Float16* h1prev, _Float16* h1out, float* creg) {
  extern __shared__ char smem[];
  int lane = tid & 63, wave = tid >> 6;
  v4f acc[4];
  acc[0] = v4f{0.f, 0.f, 0.f, 0.f}; acc[1] = acc[0]; acc[2] = acc[0]; acc[3] = acc[0];
  const char* wbLane = smem + WOFF + (size_t)lane * 16;
  int rt = (m0 >> 4) + wave;
  waitCnts(cnt0, cnt1, tR0, tR1);   // h0(cur) + h1(prev)+reuse, one wait
  mfmaDual(h0src, h1prev, rt, lane, wbLane, acc);
  epilogue(tid, m0, hc0, 0, h1out, creg, acc);
  signalDone(cnt1);
}

// dec0 gemm step (after proj): wait role0 -> h chunks -> rank1 epilogue.
static __device__ __attribute__((noinline)) void stepDec0(
    int tid, int m0, int hc0, unsigned* cnt0, unsigned* cnt1, int u,
    const _Float16* h0prev, _Float16* h0out, float* creg) {
  extern __shared__ char smem[];
  int lane = tid & 63, wave = tid >> 6;
  v4f acc[4];
  acc[0] = v4f{0.f, 0.f, 0.f, 0.f}; acc[1] = acc[0]; acc[2] = acc[0]; acc[3] = acc[0];
  const char* wbLane = smem + WOFF + (size_t)lane * 16;
  waitCnts(cnt0, cnt1, u + 1, 0);   // h0(t-1) ready (own role)
  mfma8<0>(h0prev, (m0 >> 4) + wave, lane, wbLane, acc);
  epilogue(tid, m0, hc0, 1, h0out, creg, acc);
  signalDone(cnt0);
}

__global__ void __launch_bounds__(256, 1)
seq2seq_kernel(const float* x,
               const float* e0wi, const float* e0wh, const float* e0bi, const float* e0bh,
               const float* e1wi, const float* e1wh, const float* e1bi, const float* e1bh,
               const float* d0wi, const float* d0wh, const float* d0bi, const float* d0bh,
               const float* d1wi, const float* d1wh, const float* d1bi, const float* d1bh,
               const float* pw, const float* pb,
               float* out, char* ws) {
  extern __shared__ char smem[];
  int tid = threadIdx.x, bid = blockIdx.x;
  int group = bid >> 6;
  int r = bid & 63;
  bool isL1 = (r >= 32);
  int hcTile = r & 31;
  int hc0 = hcTile * 16;
  int m0 = group * 64;
  // Aggregate counters: 64B-strided per (group, role).
  unsigned* cnt0 = (unsigned*)(ws + WS_CNT) + (size_t)group * 32;
  unsigned* cnt1 = cnt0 + 16;

  _Float16* h0b[4]; _Float16* h1b[2];
  h0b[0] = (_Float16*)(ws + WS_HOFF);
  h0b[1] = (_Float16*)(ws + WS_HOFF + 1 * HBYTES);
  h0b[2] = (_Float16*)(ws + WS_HOFF + 2 * HBYTES);
  h0b[3] = (_Float16*)(ws + WS_HOFF + 3 * HBYTES);
  h1b[0] = (_Float16*)(ws + WS_HOFF + 4 * HBYTES);
  h1b[1] = (_Float16*)(ws + WS_HOFF + 5 * HBYTES);

  float creg[4];
  creg[0] = 0.f; creg[1] = 0.f; creg[2] = 0.f; creg[3] = 0.f;

  // zero the "step -1" buffers (h0[3], h1[1]) group slice
  {
    int t16 = r * 256 + tid;
    char* base = (t16 < 8192) ? (char*)h0b[3] : (char*)h1b[1];
    int idx = t16 & 8191;
    astore8z(base + (size_t)m0 * HHD * 2 + (size_t)idx * 8);
  }

  if (!isL1) {
    loadWeights(tid, hc0, e0wi, 64, 64, e0wh, 576);
    if (tid < 64) {
      int n = (tid >> 4) * HHD + hc0 + (tid & 15);
      ((float*)(smem + BIAS_OFF))[tid] = e0bi[n] + e0bh[n];
    }
  } else {
    loadWeights(tid, hc0, e1wi, 512, 512, e1wh, 1024);
    if (tid < 64) {
      int n = (tid >> 4) * HHD + hc0 + (tid & 15);
      ((float*)(smem + BIAS_OFF))[tid] = e1bi[n] + e1bh[n];
    }
  }
  signalDone(isL1 ? cnt1 : cnt0);   // level 1 (zeros + weights done)

  if (!isL1) {
    // ---------------- encoder layer 0 ----------------
    for (int p = 0; p < TINN; ++p)
      stepEnc0(tid, m0, hc0, cnt0, cnt1, p, x + (size_t)p * FF,
               h0b[(p + 3) & 3], h0b[p & 3], creg);
    // ---------------- decoder layer 0 ----------------
    loadWeights(tid, hc0, d0wh, 512, 512, nullptr, 512);
    if (tid < 64) {
      int n = (tid >> 4) * HHD + hc0 + (tid & 15);
      ((float*)(smem + BIAS_OFF))[tid] = d0bi[n] + d0bh[n];
      ((float*)(smem + WIH0_OFF))[tid] = d0wi[n];
    }
    for (int k = tid; k < 512; k += 256) ((float*)(smem + PROJW_OFF))[k] = pw[k];
    if (tid == 0) ((float*)(smem + PROJB_OFF))[0] = pb[0];
    __syncthreads();
    for (int t = 0; t <= TOUTN; ++t) {
      int u = TINN + t;
      waitCnts(cnt0, cnt1, 0, u + 1);   // h1(t-1) ready
      float* prevl = (float*)(smem + PREV_OFF);
      if (t == 0) {
        if (tid < 64)
          prevl[tid] = x[(size_t)(m0 + tid) * (TINN * FF) + 511 * 64 + 63];
      } else {
        float* part = (float*)(smem + PART_OFF);
        float* pjw = (float*)(smem + PROJW_OFF);
        const _Float16* h1base = h1b[(u + 1) & 1];
        int m = m0 + (tid >> 2);
        int rt = m >> 4, l15m = m & 15;
        int kc0 = (tid & 3) * 2;
        float s = 0.f;
#pragma unroll
        for (int kc = kc0; kc < kc0 + 2; ++kc)
#pragma unroll
          for (int ks = 0; ks < 2; ++ks)
#pragma unroll
            for (int q = 0; q < 4; ++q) {
              int off = (rt * 8 + kc) * 2048 + ks * 1024 + q * 256 + l15m * 16;
              v8h hv = aload16(h1base + off / 2);
              const float* w = pjw + kc * 64 + ks * 32 + q * 8;
#pragma unroll
              for (int e = 0; e < 8; ++e) s += (float)hv[e] * w[e];
            }
        part[tid] = s;
        __syncthreads();
        if (tid < 64) {
          float p4 = part[tid * 4] + part[tid * 4 + 1] + part[tid * 4 + 2] +
                     part[tid * 4 + 3] + ((float*)(smem + PROJB_OFF))[0];
          prevl[tid] = p4;
          if (hcTile == 0) out[(size_t)(m0 + tid) * TOUTN + (t - 1)] = p4;
        }
      }
      __syncthreads();
      if (t < TOUTN)
        stepDec0(tid, m0, hc0, cnt0, cnt1, u, h0b[(u + 3) & 3], h0b[u & 3], creg);
    }
  } else {
    // ---------------- encoder layer 1 ----------------
    for (int s = 0; s < TINN; ++s)
      stepL1(tid, m0, hc0, cnt0, cnt1, s + 1, s + 2,
             h0b[s & 3], h1b[(s + 1) & 1], h1b[s & 1], creg);
    // ---------------- decoder layer 1 ----------------
    loadWeights(tid, hc0, d1wi, 512, 512, d1wh, 1024);
    if (tid < 64) {
      int n = (tid >> 4) * HHD + hc0 + (tid & 15);
      ((float*)(smem + BIAS_OFF))[tid] = d1bi[n] + d1bh[n];
    }
    for (int t = 0; t < TOUTN; ++t) {
      int u = TINN + t;
      stepL1(tid, m0, hc0, cnt0, cnt1, u + 1, u + 2,
             h0b[u & 3], h1b[(u + 1) & 1], h1b[u & 1], creg);
    }
  }
}

extern "C" void kernel_launch(void* const* d_in, const int* in_sizes, int n_in,
                              void* d_out, int out_size, void* d_ws, size_t ws_size,
                              hipStream_t stream) {
  const float* x = (const float*)d_in[0];
  const float* e0wi = (const float*)d_in[2];
  const float* e0wh = (const float*)d_in[3];
  const float* e0bi = (const float*)d_in[4];
  const float* e0bh = (const float*)d_in[5];
  const float* e1wi = (const float*)d_in[6];
  const float* e1wh = (const float*)d_in[7];
  const float* e1bi = (const float*)d_in[8];
  const float* e1bh = (const float*)d_in[9];
  const float* d0wi = (const float*)d_in[10];
  const float* d0wh = (const float*)d_in[11];
  const float* d0bi = (const float*)d_in[12];
  const float* d0bh = (const float*)d_in[13];
  const float* d1wi = (const float*)d_in[14];
  const float* d1wh = (const float*)d_in[15];
  const float* d1bi = (const float*)d_in[16];
  const float* d1bh = (const float*)d_in[17];
  const float* pw = (const float*)d_in[18];
  const float* pb = (const float*)d_in[19];

  (void)hipFuncSetAttribute((const void*)seq2seq_kernel,
                            hipFuncAttributeMaxDynamicSharedMemorySize, SMEM_TOTAL);
  (void)hipMemsetAsync(d_ws, 0, 16384, stream);  // counters
  seq2seq_kernel<<<dim3(256), dim3(256), SMEM_TOTAL, stream>>>(
      x, e0wi, e0wh, e0bi, e0bh, e1wi, e1wh, e1bi, e1bh,
      d0wi, d0wh, d0bi, d0bh, d1wi, d1wh, d1bi, d1bh,
      pw, pb, (float*)d_out, (char*)d_ws);
}